// Round 4
// baseline (134.134 us; speedup 1.0000x reference)
//
#include <hip/hip_runtime.h>
#include <hip/hip_bf16.h>
#include <hip/hip_cooperative_groups.h>

namespace cg = cooperative_groups;

// Problem constants (from reference):
#define B 4
#define N 256
#define F 128
#define H 256
// OUT = 1

#define SA 34  // LDS stride for [h][row] tiles: 2-way bank alias on write (free),
               // float2 reads at even offsets -> conflict-free

// ---------------------------------------------------------------------------
// Single cooperative kernel, grid = 256 blocks x 256 threads (1 block/CU).
// Phase A (per block: 4 rows): A[b,i,:] = relu(x[b,i,:]) @ W1[F:2F,:]
//                              W[b,j,:] = relu(x[b,j,:]) @ W1[2F:3F,:]
//   blocks 0..3 additionally compute the pooled path for batch == blk:
//   ub[b,h] = b1[h] + relu((mean_i x[b,i,:]) @ Wp) @ W1[0:F,:]
// grid.sync()
// Phase B (per block: one 32x32 output tile, full H in LDS, 2x2/thread):
//   out[b,i,j] = b2 + sum_h relu((A[b,i,h]+ub[b,h]) + W[b,j,h]) * W2[h]
// ---------------------------------------------------------------------------
__global__ __launch_bounds__(256) void kFused(
    const float* __restrict__ x, const float* __restrict__ Wp,
    const float* __restrict__ W1, const float* __restrict__ b1,
    const float* __restrict__ W2, const float* __restrict__ b2,
    float* __restrict__ ub, float* __restrict__ A, float* __restrict__ W,
    float* __restrict__ out) {
  __shared__ float xr[4][F];       // 2 KB   (phase A row stage)
  __shared__ float aT[256 * SA];   // 34.8 KB (phase B, [h][i-row])
  __shared__ float wT[256 * SA];   // 34.8 KB (phase B, [h][j-row])
  __shared__ float w2s[H];         // 1 KB
  __shared__ float4 red4[256];     // 4 KB   (pooled scratch)
  __shared__ float xm_s[F];
  __shared__ float rp_s[F];
  __shared__ float part[256];
  // total ~78.6 KB LDS -> fits; grid 256 = 1 block/CU (co-residency trivial)

  const int blk = blockIdx.x;
  const int t = threadIdx.x;
  const int b = blk >> 6;

  // ======================= Phase A: A/W rows =========================
  const int i0 = (blk & 63) * 4;
  {
    const int r = t >> 7, f = t & 127;  // 2 of 4 rows per thread
    xr[r][f]     = fmaxf(x[(b * N + i0 + r) * F + f], 0.f);
    xr[r + 2][f] = fmaxf(x[(b * N + i0 + r + 2) * F + f], 0.f);
  }
  __syncthreads();

  {
    float a0 = 0.f, a1 = 0.f, a2 = 0.f, a3 = 0.f;
    float q0 = 0.f, q1 = 0.f, q2 = 0.f, q3 = 0.f;
    const float* W1i = W1 + F * H;        // rows F..2F-1
    const float* W1j = W1 + 2 * F * H;    // rows 2F..3F-1
#pragma unroll 4
    for (int f = 0; f < F; ++f) {
      const float wi = W1i[f * H + t];
      const float wj = W1j[f * H + t];
      const float x0 = xr[0][f], x1 = xr[1][f];
      const float x2 = xr[2][f], x3 = xr[3][f];
      a0 = fmaf(x0, wi, a0); a1 = fmaf(x1, wi, a1);
      a2 = fmaf(x2, wi, a2); a3 = fmaf(x3, wi, a3);
      q0 = fmaf(x0, wj, q0); q1 = fmaf(x1, wj, q1);
      q2 = fmaf(x2, wj, q2); q3 = fmaf(x3, wj, q3);
    }
    A[(b * N + i0 + 0) * H + t] = a0;
    A[(b * N + i0 + 1) * H + t] = a1;
    A[(b * N + i0 + 2) * H + t] = a2;
    A[(b * N + i0 + 3) * H + t] = a3;
    W[(b * N + i0 + 0) * H + t] = q0;
    W[(b * N + i0 + 1) * H + t] = q1;
    W[(b * N + i0 + 2) * H + t] = q2;
    W[(b * N + i0 + 3) * H + t] = q3;
  }

  // -------- pooled path: blocks 0..B-1 only (uniform branch) --------
  if (blk < B) {
    const int pb = blk;
    const float4* xb4 = (const float4*)(x + pb * N * F);
    float4 acc = make_float4(0.f, 0.f, 0.f, 0.f);
#pragma unroll 8
    for (int k = 0; k < 32; ++k) {  // 8192 float4; col-group = t & 31
      const float4 v = xb4[t + 256 * k];
      acc.x += v.x; acc.y += v.y; acc.z += v.z; acc.w += v.w;
    }
    red4[t] = acc;
    __syncthreads();
    if (t < 32) {
      float4 s = red4[t];
#pragma unroll
      for (int m = 1; m < 8; ++m) {
        const float4 v = red4[t + 32 * m];
        s.x += v.x; s.y += v.y; s.z += v.z; s.w += v.w;
      }
      const float inv = 1.f / (float)N;
      xm_s[4 * t + 0] = s.x * inv;
      xm_s[4 * t + 1] = s.y * inv;
      xm_s[4 * t + 2] = s.z * inv;
      xm_s[4 * t + 3] = s.w * inv;
    }
    __syncthreads();
    // rp = relu(xm @ Wp): 2 threads per output, 64 MACs each
    {
      const int lo = t & 127, kh = t >> 7;
      float p = 0.f;
      const int k0 = kh * 64;
#pragma unroll 8
      for (int kk = 0; kk < 64; ++kk) {
        const int k = k0 + kk;
        p = fmaf(xm_s[k], Wp[k * F + lo], p);
      }
      part[t] = p;
    }
    __syncthreads();
    if (t < 128) rp_s[t] = fmaxf(part[t] + part[t + 128], 0.f);
    __syncthreads();
    {
      float u = b1[t];
#pragma unroll 8
      for (int k = 0; k < F; ++k) u = fmaf(rp_s[k], W1[k * H + t], u);
      ub[pb * H + t] = u;
    }
  }

  // =================== grid-wide barrier (device fence) ==============
  cg::this_grid().sync();

  // ======================= Phase B: pairwise tile ====================
  const int jt = blk & 7;
  const int it = (blk >> 3) & 7;
  const int i0b = it * 32;
  const int j0b = jt * 32;

  w2s[t] = W2[t];
  const float ubv = ub[b * H + t];  // h = t; fold ub during staging
  const float* Ab = A + (b * N + i0b) * H;
  const float* Wb = W + (b * N + j0b) * H;
#pragma unroll 8
  for (int r = 0; r < 32; ++r) {
    aT[t * SA + r] = Ab[r * H + t] + ubv;  // coalesced global, 2-way LDS write
    wT[t * SA + r] = Wb[r * H + t];
  }
  __syncthreads();

  const int tj = t & 15;   // j-pair 0..15
  const int ti = t >> 4;   // i-pair 0..15
  float acc00 = 0.f, acc01 = 0.f, acc10 = 0.f, acc11 = 0.f;
  const float* ap = aT + 2 * ti;
  const float* wp = wT + 2 * tj;
#pragma unroll 8
  for (int h = 0; h < 256; ++h) {
    const float2 av = *(const float2*)(ap + h * SA);
    const float2 wv = *(const float2*)(wp + h * SA);
    const float w2h = w2s[h];
    acc00 = fmaf(fmaxf(av.x + wv.x, 0.f), w2h, acc00);
    acc01 = fmaf(fmaxf(av.x + wv.y, 0.f), w2h, acc01);
    acc10 = fmaf(fmaxf(av.y + wv.x, 0.f), w2h, acc10);
    acc11 = fmaf(fmaxf(av.y + wv.y, 0.f), w2h, acc11);
  }

  const float bb = b2[0];
  const int i = i0b + 2 * ti;
  const int j = j0b + 2 * tj;
  float* o0 = out + (b * N + i) * N + j;
  o0[0] = acc00 + bb;
  o0[1] = acc01 + bb;
  o0[N] = acc10 + bb;
  o0[N + 1] = acc11 + bb;
}

extern "C" void kernel_launch(void* const* d_in, const int* in_sizes, int n_in,
                              void* d_out, int out_size, void* d_ws, size_t ws_size,
                              hipStream_t stream) {
  const float* x  = (const float*)d_in[0];  // [B,N,F]
  const float* Wp = (const float*)d_in[1];  // [F,F]
  const float* W1 = (const float*)d_in[2];  // [3F,H]
  const float* b1 = (const float*)d_in[3];  // [H]
  const float* W2 = (const float*)d_in[4];  // [H,1]
  const float* b2 = (const float*)d_in[5];  // [1]
  float* out = (float*)d_out;               // [B,N,N,1]

  float* ws = (float*)d_ws;
  float* ub = ws;                 // B*H   = 1024
  float* A  = ub + B * H;         // B*N*H = 262144
  float* W  = A + B * N * H;      // B*N*H = 262144
  // 2.1 MB of d_ws; every element written in phase A before phase B reads

  void* args[] = {(void*)&x, (void*)&Wp, (void*)&W1, (void*)&b1,
                  (void*)&W2, (void*)&b2, (void*)&ub, (void*)&A,
                  (void*)&W, (void*)&out};
  hipLaunchCooperativeKernel((const void*)kFused, dim3(256), dim3(256),
                             args, 0, stream);
}

// Round 5
// 96.714 us; speedup vs baseline: 1.3869x; 1.3869x over previous
//
#include <hip/hip_runtime.h>
#include <hip/hip_bf16.h>

// Problem constants (from reference):
#define B 4
#define N 256
#define F 128
#define H 256
// OUT = 1

// ---------------------------------------------------------------------------
// kAW: A[b,i,h] = relu(x[b,i,:]) @ W1[F:2F, :]     (ub folded later, in kPair)
//      W[b,j,h] = relu(x[b,j,:]) @ W1[2F:3F, :]
// grid = 256 blocks = 128 row-groups x 2 h-halves; each block: 8 rows, 128 h.
// (h-split halves per-block W1 traffic: 128 KB/block, 32 MB total from L2.)
// Blocks 0..B-1 additionally compute the pooled path for batch == blk:
//   ub[b,h] = b1[h] + relu((mean_i x[b,i,:]) @ Wp) @ W1[0:F,:]
// ---------------------------------------------------------------------------
__global__ __launch_bounds__(256) void kAW(
    const float* __restrict__ x, const float* __restrict__ Wp,
    const float* __restrict__ W1, const float* __restrict__ b1,
    float* __restrict__ ub, float* __restrict__ A, float* __restrict__ W) {
  __shared__ float xr[8][F];      // 4 KB: 8 relu'd input rows
  const int blk = blockIdx.x;
  const int rg = blk >> 1;        // row-group 0..127
  const int hh = blk & 1;         // h-half
  const int b = rg >> 5;          // 32 row-groups per batch
  const int i0 = (rg & 31) * 8;
  const int t = threadIdx.x;
  const int h = hh * 128 + (t & 127);
  const int rh = (t >> 7) * 4;    // rows 0..3 or 4..7

  // stage 8 relu'd rows (1024 floats, 4 per thread, coalesced)
#pragma unroll
  for (int idx = t; idx < 8 * F; idx += 256) {
    const int r = idx >> 7, f = idx & 127;
    xr[r][f] = fmaxf(x[(b * N + i0 + r) * F + f], 0.f);
  }
  __syncthreads();

  {
    float a0 = 0.f, a1 = 0.f, a2 = 0.f, a3 = 0.f;
    float q0 = 0.f, q1 = 0.f, q2 = 0.f, q3 = 0.f;
    const float* W1i = W1 + F * H;       // rows F..2F-1
    const float* W1j = W1 + 2 * F * H;   // rows 2F..3F-1
#pragma unroll 4
    for (int f = 0; f < F; ++f) {
      const float wi = W1i[f * H + h];   // coalesced 256 B / wave
      const float wj = W1j[f * H + h];
      const float x0 = xr[rh + 0][f];    // LDS broadcast (wave-uniform addr)
      const float x1 = xr[rh + 1][f];
      const float x2 = xr[rh + 2][f];
      const float x3 = xr[rh + 3][f];
      a0 = fmaf(x0, wi, a0); a1 = fmaf(x1, wi, a1);
      a2 = fmaf(x2, wi, a2); a3 = fmaf(x3, wi, a3);
      q0 = fmaf(x0, wj, q0); q1 = fmaf(x1, wj, q1);
      q2 = fmaf(x2, wj, q2); q3 = fmaf(x3, wj, q3);
    }
    A[(b * N + i0 + rh + 0) * H + h] = a0;
    A[(b * N + i0 + rh + 1) * H + h] = a1;
    A[(b * N + i0 + rh + 2) * H + h] = a2;
    A[(b * N + i0 + rh + 3) * H + h] = a3;
    W[(b * N + i0 + rh + 0) * H + h] = q0;
    W[(b * N + i0 + rh + 1) * H + h] = q1;
    W[(b * N + i0 + rh + 2) * H + h] = q2;
    W[(b * N + i0 + rh + 3) * H + h] = q3;
  }

  // -------- pooled path: blocks 0..B-1 only (uniform branch) --------
  if (blk < B) {
    __shared__ float4 red4[256];
    __shared__ float xm_s[F];
    __shared__ float rp_s[F];
    __shared__ float part[256];
    const int pb = blk;
    const float4* xb4 = (const float4*)(x + pb * N * F);
    float4 acc = make_float4(0.f, 0.f, 0.f, 0.f);
#pragma unroll 8
    for (int k = 0; k < 32; ++k) {  // 8192 float4; col-group = t & 31
      const float4 v = xb4[t + 256 * k];
      acc.x += v.x; acc.y += v.y; acc.z += v.z; acc.w += v.w;
    }
    red4[t] = acc;
    __syncthreads();
    if (t < 32) {
      float4 s = red4[t];
#pragma unroll
      for (int m = 1; m < 8; ++m) {
        const float4 v = red4[t + 32 * m];
        s.x += v.x; s.y += v.y; s.z += v.z; s.w += v.w;
      }
      const float inv = 1.f / (float)N;
      xm_s[4 * t + 0] = s.x * inv;
      xm_s[4 * t + 1] = s.y * inv;
      xm_s[4 * t + 2] = s.z * inv;
      xm_s[4 * t + 3] = s.w * inv;
    }
    __syncthreads();
    // rp = relu(xm @ Wp): 2 threads per output, 64 MACs each
    {
      const int lo = t & 127, kh = t >> 7;
      float p = 0.f;
      const int k0 = kh * 64;
#pragma unroll 8
      for (int kk = 0; kk < 64; ++kk) {
        const int k = k0 + kk;
        p = fmaf(xm_s[k], Wp[k * F + lo], p);
      }
      part[t] = p;
    }
    __syncthreads();
    if (t < 128) rp_s[t] = fmaxf(part[t] + part[t + 128], 0.f);
    __syncthreads();
    {
      float u = b1[t];
#pragma unroll 8
      for (int k = 0; k < F; ++k) u = fmaf(rp_s[k], W1[k * H + t], u);
      ub[pb * H + t] = u;
    }
  }
}

// ---------------------------------------------------------------------------
// kPair: out[b,i,j] = b2 + sum_h relu((A[b,i,h]+ub[b,h]) + W[b,j,h]) * W2[h]
// 32x32 tile, 2x2 per thread (float2 LDS reads), full H=256 in-block.
// grid = (8, 8, B) = 256 blocks (1/CU), block = 256.
// LDS: aT/wT [h][row] stride 34 (~69.6 KB) + w2s. Reads conflict-free
// (a: 4 addrs x16-bcast; w: 32 consecutive floats = all banks). Staging
// writes are 4-way aliased (1.58x on ~1.5k cyc -- accepted). w2 read as
// float4 per 4 h to amortize the broadcast read.
// ---------------------------------------------------------------------------
#define SA 34
__global__ __launch_bounds__(256) void kPair(
    const float* __restrict__ A, const float* __restrict__ W,
    const float* __restrict__ ub, const float* __restrict__ W2,
    const float* __restrict__ b2, float* __restrict__ out) {
  __shared__ float aT[256 * SA];  // [h][i-row 0..31]
  __shared__ float wT[256 * SA];  // [h][j-row 0..31]
  __shared__ float w2s[H];

  const int b = blockIdx.z;
  const int i0 = blockIdx.y * 32;
  const int j0 = blockIdx.x * 32;
  const int t = threadIdx.x;      // = h during staging

  w2s[t] = W2[t];
  const float ubv = ub[b * H + t];  // fold ub while staging (h = t)
  const float* Ab = A + (b * N + i0) * H;
  const float* Wb = W + (b * N + j0) * H;
#pragma unroll 8
  for (int r = 0; r < 32; ++r) {
    aT[t * SA + r] = Ab[r * H + t] + ubv;  // coalesced global read
    wT[t * SA + r] = Wb[r * H + t];
  }
  __syncthreads();

  const int tj = t & 15;   // j-pair
  const int ti = t >> 4;   // i-pair
  float acc00 = 0.f, acc01 = 0.f, acc10 = 0.f, acc11 = 0.f;
  const float* ap = aT + 2 * ti;
  const float* wp = wT + 2 * tj;
#pragma unroll 4
  for (int h4 = 0; h4 < 256; h4 += 4) {
    const float4 w2v = *(const float4*)(w2s + h4);
#pragma unroll
    for (int k = 0; k < 4; ++k) {
      const int h = h4 + k;
      const float2 av = *(const float2*)(ap + h * SA);
      const float2 wv = *(const float2*)(wp + h * SA);
      const float w2h = (k == 0) ? w2v.x : (k == 1) ? w2v.y
                       : (k == 2) ? w2v.z : w2v.w;
      acc00 = fmaf(fmaxf(av.x + wv.x, 0.f), w2h, acc00);
      acc01 = fmaf(fmaxf(av.x + wv.y, 0.f), w2h, acc01);
      acc10 = fmaf(fmaxf(av.y + wv.x, 0.f), w2h, acc10);
      acc11 = fmaf(fmaxf(av.y + wv.y, 0.f), w2h, acc11);
    }
  }

  const float bb = b2[0];
  const int i = i0 + 2 * ti;
  const int j = j0 + 2 * tj;
  float* o0 = out + (b * N + i) * N + j;
  o0[0] = acc00 + bb;
  o0[1] = acc01 + bb;
  o0[N] = acc10 + bb;
  o0[N + 1] = acc11 + bb;
}

extern "C" void kernel_launch(void* const* d_in, const int* in_sizes, int n_in,
                              void* d_out, int out_size, void* d_ws, size_t ws_size,
                              hipStream_t stream) {
  const float* x  = (const float*)d_in[0];  // [B,N,F]
  const float* Wp = (const float*)d_in[1];  // [F,F]
  const float* W1 = (const float*)d_in[2];  // [3F,H]
  const float* b1 = (const float*)d_in[3];  // [H]
  const float* W2 = (const float*)d_in[4];  // [H,1]
  const float* b2 = (const float*)d_in[5];  // [1]
  float* out = (float*)d_out;               // [B,N,N,1]

  float* ws = (float*)d_ws;
  float* ub = ws;                 // B*H   = 1024
  float* A  = ub + B * H;         // B*N*H = 262144
  float* W  = A + B * N * H;      // B*N*H = 262144
  // 2.1 MB of d_ws; every element written by kAW before kPair reads it

  kAW<<<dim3(256), dim3(256), 0, stream>>>(x, Wp, W1, b1, ub, A, W);
  kPair<<<dim3(N / 32, N / 32, B), dim3(256), 0, stream>>>(A, W, ub, W2, b2, out);
}

// Round 6
// 95.019 us; speedup vs baseline: 1.4117x; 1.0178x over previous
//
#include <hip/hip_runtime.h>
#include <hip/hip_bf16.h>

// Problem constants (from reference):
#define B 4
#define N 256
#define F 128
#define H 256
// OUT = 1

// ---------------------------------------------------------------------------
// kAW: A[b,i,h] = relu(x[b,i,:]) @ W1[F:2F, :]     (ub folded later, in kPair)
//      W[b,j,h] = relu(x[b,j,:]) @ W1[2F:3F, :]
// grid = 512 blocks = 128 row-groups(4 rows) x 2 h-halves; 2 blocks/CU
// (8 waves/CU = 2 waves/SIMD -- latency hiding; R5's 256-block variant was
//  1 wave/SIMD and regressed ~2x on exposed L2 latency).
// Per thread: 2 rows x 2 mats x 128 f = 512 FMA. W1 L2 traffic 64 MB total.
// Blocks 0..B-1 additionally compute the pooled path for batch == blk:
//   ub[b,h] = b1[h] + relu((mean_i x[b,i,:]) @ Wp) @ W1[0:F,:]
// ---------------------------------------------------------------------------
__global__ __launch_bounds__(256) void kAW(
    const float* __restrict__ x, const float* __restrict__ Wp,
    const float* __restrict__ W1, const float* __restrict__ b1,
    float* __restrict__ ub, float* __restrict__ A, float* __restrict__ W) {
  __shared__ float xr[4][F];      // 2 KB: 4 relu'd input rows
  const int blk = blockIdx.x;
  const int rg = blk >> 1;        // row-group 0..255
  const int hh = blk & 1;         // h-half
  const int b = rg >> 6;          // 64 row-groups per batch
  const int i0 = (rg & 63) * 4;
  const int t = threadIdx.x;
  const int h = hh * 128 + (t & 127);
  const int rh = (t >> 7) * 2;    // rows {0,1} or {2,3}

  // stage 4 relu'd rows (512 floats, 2 per thread, coalesced)
  {
    const int idx0 = t, idx1 = t + 256;
    xr[idx0 >> 7][idx0 & 127] =
        fmaxf(x[(b * N + i0 + (idx0 >> 7)) * F + (idx0 & 127)], 0.f);
    xr[idx1 >> 7][idx1 & 127] =
        fmaxf(x[(b * N + i0 + (idx1 >> 7)) * F + (idx1 & 127)], 0.f);
  }
  __syncthreads();

  {
    float a0 = 0.f, a1 = 0.f, q0 = 0.f, q1 = 0.f;
    const float* W1i = W1 + F * H;       // rows F..2F-1
    const float* W1j = W1 + 2 * F * H;   // rows 2F..3F-1
#pragma unroll 8
    for (int f = 0; f < F; ++f) {
      const float wi = W1i[f * H + h];   // coalesced 256 B / wave
      const float wj = W1j[f * H + h];
      const float x0 = xr[rh + 0][f];    // LDS wave-uniform broadcast
      const float x1 = xr[rh + 1][f];
      a0 = fmaf(x0, wi, a0); a1 = fmaf(x1, wi, a1);
      q0 = fmaf(x0, wj, q0); q1 = fmaf(x1, wj, q1);
    }
    A[(b * N + i0 + rh + 0) * H + h] = a0;
    A[(b * N + i0 + rh + 1) * H + h] = a1;
    W[(b * N + i0 + rh + 0) * H + h] = q0;
    W[(b * N + i0 + rh + 1) * H + h] = q1;
  }

  // -------- pooled path: blocks 0..B-1 only (uniform branch) --------
  if (blk < B) {
    __shared__ float4 red4[256];
    __shared__ float xm_s[F];
    __shared__ float rp_s[F];
    __shared__ float part[256];
    const int pb = blk;
    const float4* xb4 = (const float4*)(x + pb * N * F);
    float4 acc = make_float4(0.f, 0.f, 0.f, 0.f);
#pragma unroll 8
    for (int k = 0; k < 32; ++k) {  // 8192 float4; col-group = t & 31
      const float4 v = xb4[t + 256 * k];
      acc.x += v.x; acc.y += v.y; acc.z += v.z; acc.w += v.w;
    }
    red4[t] = acc;
    __syncthreads();
    if (t < 32) {
      float4 s = red4[t];
#pragma unroll
      for (int m = 1; m < 8; ++m) {
        const float4 v = red4[t + 32 * m];
        s.x += v.x; s.y += v.y; s.z += v.z; s.w += v.w;
      }
      const float inv = 1.f / (float)N;
      xm_s[4 * t + 0] = s.x * inv;
      xm_s[4 * t + 1] = s.y * inv;
      xm_s[4 * t + 2] = s.z * inv;
      xm_s[4 * t + 3] = s.w * inv;
    }
    __syncthreads();
    // rp = relu(xm @ Wp): 2 threads per output, 64 MACs each
    {
      const int lo = t & 127, kh = t >> 7;
      float p = 0.f;
      const int k0 = kh * 64;
#pragma unroll 8
      for (int kk = 0; kk < 64; ++kk) {
        const int k = k0 + kk;
        p = fmaf(xm_s[k], Wp[k * F + lo], p);
      }
      part[t] = p;
    }
    __syncthreads();
    if (t < 128) rp_s[t] = fmaxf(part[t] + part[t + 128], 0.f);
    __syncthreads();
    {
      float u = b1[t];
#pragma unroll 8
      for (int k = 0; k < F; ++k) u = fmaf(rp_s[k], W1[k * H + t], u);
      ub[pb * H + t] = u;
    }
  }
}

// ---------------------------------------------------------------------------
// kPair: out[b,i,j] = b2 + sum_h relu((A[b,i,h]+ub[b,h]) + W[b,j,h]) * W2[h]
// 32x32 tile, 2x2 per thread (float2 LDS reads), full H=256 in-block.
// grid = (8, 8, B) = 256 blocks (1/CU), block = 256.
// LDS ~70 KB. Inner-loop reads conflict-free (a: 16 float2 addrs covering
// all banks w/ 4-way broadcast; w: same). Staging writes 4-way aliased
// (1.58x on ~small staging phase -- accepted). w2 via float4 per 4 h.
// LDS-traffic floor: 256h x 4KB = 1 MB/CU ~= 3.4 us.
// ---------------------------------------------------------------------------
#define SA 34
__global__ __launch_bounds__(256) void kPair(
    const float* __restrict__ A, const float* __restrict__ W,
    const float* __restrict__ ub, const float* __restrict__ W2,
    const float* __restrict__ b2, float* __restrict__ out) {
  __shared__ float aT[256 * SA];  // [h][i-row 0..31]
  __shared__ float wT[256 * SA];  // [h][j-row 0..31]
  __shared__ float w2s[H];

  const int b = blockIdx.z;
  const int i0 = blockIdx.y * 32;
  const int j0 = blockIdx.x * 32;
  const int t = threadIdx.x;      // = h during staging

  w2s[t] = W2[t];
  const float ubv = ub[b * H + t];  // fold ub while staging (h = t)
  const float* Ab = A + (b * N + i0) * H;
  const float* Wb = W + (b * N + j0) * H;
#pragma unroll 8
  for (int r = 0; r < 32; ++r) {
    aT[t * SA + r] = Ab[r * H + t] + ubv;  // coalesced global read
    wT[t * SA + r] = Wb[r * H + t];
  }
  __syncthreads();

  const int tj = t & 15;   // j-pair
  const int ti = t >> 4;   // i-pair
  float acc00 = 0.f, acc01 = 0.f, acc10 = 0.f, acc11 = 0.f;
  const float* ap = aT + 2 * ti;
  const float* wp = wT + 2 * tj;
#pragma unroll 4
  for (int h4 = 0; h4 < 256; h4 += 4) {
    const float4 w2v = *(const float4*)(w2s + h4);
#pragma unroll
    for (int k = 0; k < 4; ++k) {
      const int h = h4 + k;
      const float2 av = *(const float2*)(ap + h * SA);
      const float2 wv = *(const float2*)(wp + h * SA);
      const float w2h = (k == 0) ? w2v.x : (k == 1) ? w2v.y
                       : (k == 2) ? w2v.z : w2v.w;
      acc00 = fmaf(fmaxf(av.x + wv.x, 0.f), w2h, acc00);
      acc01 = fmaf(fmaxf(av.x + wv.y, 0.f), w2h, acc01);
      acc10 = fmaf(fmaxf(av.y + wv.x, 0.f), w2h, acc10);
      acc11 = fmaf(fmaxf(av.y + wv.y, 0.f), w2h, acc11);
    }
  }

  const float bb = b2[0];
  const int i = i0 + 2 * ti;
  const int j = j0 + 2 * tj;
  float* o0 = out + (b * N + i) * N + j;
  o0[0] = acc00 + bb;
  o0[1] = acc01 + bb;
  o0[N] = acc10 + bb;
  o0[N + 1] = acc11 + bb;
}

extern "C" void kernel_launch(void* const* d_in, const int* in_sizes, int n_in,
                              void* d_out, int out_size, void* d_ws, size_t ws_size,
                              hipStream_t stream) {
  const float* x  = (const float*)d_in[0];  // [B,N,F]
  const float* Wp = (const float*)d_in[1];  // [F,F]
  const float* W1 = (const float*)d_in[2];  // [3F,H]
  const float* b1 = (const float*)d_in[3];  // [H]
  const float* W2 = (const float*)d_in[4];  // [H,1]
  const float* b2 = (const float*)d_in[5];  // [1]
  float* out = (float*)d_out;               // [B,N,N,1]

  float* ws = (float*)d_ws;
  float* ub = ws;                 // B*H   = 1024
  float* A  = ub + B * H;         // B*N*H = 262144
  float* W  = A + B * N * H;      // B*N*H = 262144
  // 2.1 MB of d_ws; every element written by kAW before kPair reads it

  kAW<<<dim3(512), dim3(256), 0, stream>>>(x, Wp, W1, b1, ub, A, W);
  kPair<<<dim3(N / 32, N / 32, B), dim3(256), 0, stream>>>(A, W, ub, W2, b2, out);
}

// Round 7
// 94.674 us; speedup vs baseline: 1.4168x; 1.0036x over previous
//
#include <hip/hip_runtime.h>
#include <hip/hip_bf16.h>

// Problem constants (from reference):
#define B 4
#define N 256
#define F 128
#define H 256
// OUT = 1

// ---------------------------------------------------------------------------
// kAW: A[b,i,h] = relu(x[b,i,:]) @ W1[F:2F, :]     (ub folded later, in kPair)
//      W[b,j,h] = relu(x[b,j,:]) @ W1[2F:3F, :]
// grid = 512 blocks = 128 row-groups(4 rows) x 2 h-halves; 2 blocks/CU
// (8 waves/CU = 2 waves/SIMD; 1 wave/SIMD variants regressed ~2x on exposed
//  L2 latency -- R5/R6 lesson). Per thread: 2 rows x 2 mats x 128 f = 512 FMA.
// Blocks 0..B-1 additionally compute the pooled path for batch == blk:
//   ub[b,h] = b1[h] + relu((mean_i x[b,i,:]) @ Wp) @ W1[0:F,:]
// ---------------------------------------------------------------------------
__global__ __launch_bounds__(256) void kAW(
    const float* __restrict__ x, const float* __restrict__ Wp,
    const float* __restrict__ W1, const float* __restrict__ b1,
    float* __restrict__ ub, float* __restrict__ A, float* __restrict__ W) {
  __shared__ float xr[4][F];      // 2 KB: 4 relu'd input rows
  const int blk = blockIdx.x;
  const int rg = blk >> 1;        // row-group 0..255
  const int hh = blk & 1;         // h-half
  const int b = rg >> 6;          // 64 row-groups per batch
  const int i0 = (rg & 63) * 4;
  const int t = threadIdx.x;
  const int h = hh * 128 + (t & 127);
  const int rh = (t >> 7) * 2;    // rows {0,1} or {2,3}

  // stage 4 relu'd rows (512 floats, 2 per thread, coalesced)
  {
    const int idx0 = t, idx1 = t + 256;
    xr[idx0 >> 7][idx0 & 127] =
        fmaxf(x[(b * N + i0 + (idx0 >> 7)) * F + (idx0 & 127)], 0.f);
    xr[idx1 >> 7][idx1 & 127] =
        fmaxf(x[(b * N + i0 + (idx1 >> 7)) * F + (idx1 & 127)], 0.f);
  }
  __syncthreads();

  {
    float a0 = 0.f, a1 = 0.f, q0 = 0.f, q1 = 0.f;
    const float* W1i = W1 + F * H;       // rows F..2F-1
    const float* W1j = W1 + 2 * F * H;   // rows 2F..3F-1
#pragma unroll 8
    for (int f = 0; f < F; ++f) {
      const float wi = W1i[f * H + h];   // coalesced 256 B / wave
      const float wj = W1j[f * H + h];
      const float x0 = xr[rh + 0][f];    // LDS wave-uniform broadcast
      const float x1 = xr[rh + 1][f];
      a0 = fmaf(x0, wi, a0); a1 = fmaf(x1, wi, a1);
      q0 = fmaf(x0, wj, q0); q1 = fmaf(x1, wj, q1);
    }
    A[(b * N + i0 + rh + 0) * H + h] = a0;
    A[(b * N + i0 + rh + 1) * H + h] = a1;
    W[(b * N + i0 + rh + 0) * H + h] = q0;
    W[(b * N + i0 + rh + 1) * H + h] = q1;
  }

  // -------- pooled path: blocks 0..B-1 only (uniform branch) --------
  if (blk < B) {
    __shared__ float4 red4[256];
    __shared__ float xm_s[F];
    __shared__ float rp_s[F];
    __shared__ float part[256];
    const int pb = blk;
    const float4* xb4 = (const float4*)(x + pb * N * F);
    float4 acc = make_float4(0.f, 0.f, 0.f, 0.f);
#pragma unroll 8
    for (int k = 0; k < 32; ++k) {  // 8192 float4; col-group = t & 31
      const float4 v = xb4[t + 256 * k];
      acc.x += v.x; acc.y += v.y; acc.z += v.z; acc.w += v.w;
    }
    red4[t] = acc;
    __syncthreads();
    if (t < 32) {
      float4 s = red4[t];
#pragma unroll
      for (int m = 1; m < 8; ++m) {
        const float4 v = red4[t + 32 * m];
        s.x += v.x; s.y += v.y; s.z += v.z; s.w += v.w;
      }
      const float inv = 1.f / (float)N;
      xm_s[4 * t + 0] = s.x * inv;
      xm_s[4 * t + 1] = s.y * inv;
      xm_s[4 * t + 2] = s.z * inv;
      xm_s[4 * t + 3] = s.w * inv;
    }
    __syncthreads();
    // rp = relu(xm @ Wp): 2 threads per output, 64 MACs each
    {
      const int lo = t & 127, kh = t >> 7;
      float p = 0.f;
      const int k0 = kh * 64;
#pragma unroll 8
      for (int kk = 0; kk < 64; ++kk) {
        const int k = k0 + kk;
        p = fmaf(xm_s[k], Wp[k * F + lo], p);
      }
      part[t] = p;
    }
    __syncthreads();
    if (t < 128) rp_s[t] = fmaxf(part[t] + part[t + 128], 0.f);
    __syncthreads();
    {
      float u = b1[t];
#pragma unroll 8
      for (int k = 0; k < F; ++k) u = fmaf(rp_s[k], W1[k * H + t], u);
      ub[pb * H + t] = u;
    }
  }
}

// ---------------------------------------------------------------------------
// kPair: out[b,i,j] = b2 + sum_h relu((A[b,i,h]+ub[b,h]) + W[b,j,h]) * W2[h]
// 32x32 tile, full H=256 in LDS, **512 threads** (8 waves/CU = 2/SIMD),
// 2 outputs per thread (2i x 1j). grid = (8, 8, B) = 256 blocks (1/CU).
// LDS ~70 KB. Per wave per h: 1 ds_read_b64 (a: 2 addrs, broadcast) +
// 1 ds_read_b32 (w: 32 consecutive -> all banks) + b128 w2 per 4h.
// Staging writes 2-way bank-aliased (free, m136). 64 KB global stage/CU.
// ---------------------------------------------------------------------------
#define SA 34
__global__ __launch_bounds__(512) void kPair(
    const float* __restrict__ A, const float* __restrict__ W,
    const float* __restrict__ ub, const float* __restrict__ W2,
    const float* __restrict__ b2, float* __restrict__ out) {
  __shared__ float aT[256 * SA];  // [h][i-row 0..31]
  __shared__ float wT[256 * SA];  // [h][j-row 0..31]
  __shared__ float w2s[H];

  const int b = blockIdx.z;
  const int i0 = blockIdx.y * 32;
  const int j0 = blockIdx.x * 32;
  const int t = threadIdx.x;       // 0..511
  const int hh = t & 255;          // h during staging (coalesced)
  const int rh = (t >> 8) * 16;    // rows 0..15 or 16..31

  if (t < H) w2s[t] = W2[t];
  const float ubv = ub[b * H + hh];  // fold ub while staging
  const float* Ab = A + (b * N + i0) * H;
  const float* Wb = W + (b * N + j0) * H;
#pragma unroll 8
  for (int k = 0; k < 16; ++k) {
    const int r = rh + k;
    aT[hh * SA + r] = Ab[r * H + hh] + ubv;  // coalesced global read
    wT[hh * SA + r] = Wb[r * H + hh];
  }
  __syncthreads();

  const int tj = t & 31;   // j col 0..31
  const int ti = t >> 5;   // i-pair 0..15
  float acc0 = 0.f, acc1 = 0.f;
  const float* ap = aT + 2 * ti;
  const float* wp = wT + tj;
#pragma unroll 4
  for (int h4 = 0; h4 < 256; h4 += 4) {
    const float4 w2v = *(const float4*)(w2s + h4);
#pragma unroll
    for (int k = 0; k < 4; ++k) {
      const int h = h4 + k;
      const float2 av = *(const float2*)(ap + h * SA);  // 2 addrs/wave
      const float wv = wp[h * SA];                      // 32 banks/wave
      const float w2h = (k == 0) ? w2v.x : (k == 1) ? w2v.y
                       : (k == 2) ? w2v.z : w2v.w;
      acc0 = fmaf(fmaxf(av.x + wv, 0.f), w2h, acc0);
      acc1 = fmaf(fmaxf(av.y + wv, 0.f), w2h, acc1);
    }
  }

  const float bb = b2[0];
  const int i = i0 + 2 * ti;
  const int j = j0 + tj;
  float* o = out + (b * N + i) * N + j;
  o[0] = acc0 + bb;
  o[N] = acc1 + bb;
}

extern "C" void kernel_launch(void* const* d_in, const int* in_sizes, int n_in,
                              void* d_out, int out_size, void* d_ws, size_t ws_size,
                              hipStream_t stream) {
  const float* x  = (const float*)d_in[0];  // [B,N,F]
  const float* Wp = (const float*)d_in[1];  // [F,F]
  const float* W1 = (const float*)d_in[2];  // [3F,H]
  const float* b1 = (const float*)d_in[3];  // [H]
  const float* W2 = (const float*)d_in[4];  // [H,1]
  const float* b2 = (const float*)d_in[5];  // [1]
  float* out = (float*)d_out;               // [B,N,N,1]

  float* ws = (float*)d_ws;
  float* ub = ws;                 // B*H   = 1024
  float* A  = ub + B * H;         // B*N*H = 262144
  float* W  = A + B * N * H;      // B*N*H = 262144
  // 2.1 MB of d_ws; every element written by kAW before kPair reads it

  kAW<<<dim3(512), dim3(256), 0, stream>>>(x, Wp, W1, b1, ub, A, W);
  kPair<<<dim3(N / 32, N / 32, B), dim3(512), 0, stream>>>(A, W, ub, W2, b2, out);
}

// Round 8
// 90.151 us; speedup vs baseline: 1.4879x; 1.0502x over previous
//
#include <hip/hip_runtime.h>
#include <hip/hip_bf16.h>

// Problem constants (from reference):
#define B 4
#define N 256
#define F 128
#define H 256
// OUT = 1

typedef _Float16 h2_t __attribute__((ext_vector_type(2)));
static __device__ __forceinline__ unsigned int h2u(h2_t v) {
  return __builtin_bit_cast(unsigned int, v);
}
static __device__ __forceinline__ h2_t uh2(unsigned int v) {
  return __builtin_bit_cast(h2_t, v);
}

// ---------------------------------------------------------------------------
// kAW: Ah[b,i,h2] = half2( relu(x[b,i,:]) @ W1[F:2F, 2h2..2h2+1] )
//      Wh[b,j,h2] = half2( relu(x[b,j,:]) @ W1[2F:3F, 2h2..2h2+1] )
// grid = 256 blocks (32 row-groups x 4 batches x 2 h-halves is folded as
// rg = blk>>1 (8 rows), hh = blk&1), block = 512 (8 waves/CU, 2/SIMD).
// Per thread: 1 row x 2 h x 2 mats x 128 f = 512 FMA. W1 L2 traffic: 32 MB.
// Blocks 0..B-1 also compute the pooled path -> ubh[b][h2] (half2):
//   ub[b,h] = b1[h] + relu((mean_i x[b,i,:]) @ Wp) @ W1[0:F,:]
// f16 rounding: err ~ 4e-3 * ||W2||_2 ~ 4e-3 << 2.7e-2 threshold.
// ---------------------------------------------------------------------------
__global__ __launch_bounds__(512) void kAW(
    const float* __restrict__ x, const float* __restrict__ Wp,
    const float* __restrict__ W1, const float* __restrict__ b1,
    unsigned int* __restrict__ ubh, unsigned int* __restrict__ Ah,
    unsigned int* __restrict__ Wh) {
  __shared__ float xr[8][F];      // 4 KB: 8 relu'd input rows
  const int blk = blockIdx.x;
  const int rg = blk >> 1;        // row-group 0..127 (8 rows each)
  const int hh = blk & 1;         // h-half
  const int b = rg >> 5;          // 32 row-groups per batch
  const int i0 = (rg & 31) * 8;
  const int t = threadIdx.x;      // 0..511
  const int h2l = t & 63;
  const int r = t >> 6;           // row 0..7
  const int h2g = hh * 64 + h2l;  // global h2 0..127

  // stage 8 relu'd rows (1024 floats, 2 per thread, coalesced)
  {
    int idx = t;
    xr[idx >> 7][idx & 127] =
        fmaxf(x[(b * N + i0 + (idx >> 7)) * F + (idx & 127)], 0.f);
    idx = t + 512;
    xr[idx >> 7][idx & 127] =
        fmaxf(x[(b * N + i0 + (idx >> 7)) * F + (idx & 127)], 0.f);
  }
  __syncthreads();

  {
    float a0 = 0.f, a1 = 0.f, q0 = 0.f, q1 = 0.f;
    const float* W1i = W1 + F * H + 2 * h2g;      // rows F..2F-1
    const float* W1j = W1 + 2 * F * H + 2 * h2g;  // rows 2F..3F-1
#pragma unroll 8
    for (int f = 0; f < F; ++f) {
      const float2 wi = *(const float2*)(W1i + f * H);  // 512 B / wave
      const float2 wj = *(const float2*)(W1j + f * H);
      const float xv = xr[r][f];                        // LDS broadcast
      a0 = fmaf(xv, wi.x, a0); a1 = fmaf(xv, wi.y, a1);
      q0 = fmaf(xv, wj.x, q0); q1 = fmaf(xv, wj.y, q1);
    }
    h2_t av; av.x = (_Float16)a0; av.y = (_Float16)a1;
    h2_t qv; qv.x = (_Float16)q0; qv.y = (_Float16)q1;
    Ah[(b * N + i0 + r) * 128 + h2g] = h2u(av);  // 256 B / wave coalesced
    Wh[(b * N + i0 + r) * 128 + h2g] = h2u(qv);
  }

  // -------- pooled path: blocks 0..B-1 only (block-uniform branch) --------
  if (blk < B) {
    __shared__ float4 red4[512];  // 8 KB
    __shared__ float xm_s[F];
    __shared__ float rp_s[F];
    __shared__ float part[512];
    const int pb = blk;
    const float4* xb4 = (const float4*)(x + pb * N * F);
    float4 acc = make_float4(0.f, 0.f, 0.f, 0.f);
#pragma unroll
    for (int k = 0; k < 16; ++k) {  // 8192 float4; col-group = t & 31
      const float4 v = xb4[t + 512 * k];
      acc.x += v.x; acc.y += v.y; acc.z += v.z; acc.w += v.w;
    }
    red4[t] = acc;
    __syncthreads();
    if (t < 32) {
      float4 s = red4[t];
#pragma unroll
      for (int m = 1; m < 16; ++m) {
        const float4 v = red4[t + 32 * m];
        s.x += v.x; s.y += v.y; s.z += v.z; s.w += v.w;
      }
      const float inv = 1.f / (float)N;
      xm_s[4 * t + 0] = s.x * inv;
      xm_s[4 * t + 1] = s.y * inv;
      xm_s[4 * t + 2] = s.z * inv;
      xm_s[4 * t + 3] = s.w * inv;
    }
    __syncthreads();
    // rp = relu(xm @ Wp): 4 threads per output, 32 MACs each
    {
      const int lo = t & 127, kh = t >> 7;  // kh 0..3
      float p = 0.f;
      const int k0 = kh * 32;
#pragma unroll 8
      for (int kk = 0; kk < 32; ++kk) {
        const int k = k0 + kk;
        p = fmaf(xm_s[k], Wp[k * F + lo], p);
      }
      part[t] = p;
    }
    __syncthreads();
    if (t < 128)
      rp_s[t] = fmaxf(part[t] + part[t + 128] + part[t + 256] + part[t + 384],
                      0.f);
    __syncthreads();
    // ub[h] = b1[h] + rp @ W1[0:F, h]: 2 threads per output, 64 MACs each
    {
      const int lo = t & 255, kh = t >> 8;
      float u = 0.f;
      const int k0 = kh * 64;
#pragma unroll 8
      for (int kk = 0; kk < 64; ++kk) {
        const int k = k0 + kk;
        u = fmaf(rp_s[k], W1[k * H + lo], u);
      }
      part[t] = u;
    }
    __syncthreads();
    if (t < 256) {
      const float u = part[t] + part[t + 256] + b1[t];
      const float un = __shfl_down(u, 1);
      if ((t & 1) == 0) {
        h2_t v; v.x = (_Float16)u; v.y = (_Float16)un;
        ubh[pb * 128 + (t >> 1)] = h2u(v);
      }
    }
  }
}

// ---------------------------------------------------------------------------
// kPair: out[b,i,j] = b2 + sum_h relu((A+ub)[b,i,h] + W[b,j,h]) * W2[h]
// 32x32 tile, 512 threads = 8 h-slices (one per wave) x 64 positions.
// Thread: 4i x 4j x 32 h (16 h2-pairs). LDS data = half2 [h2][row], stride 36
// (b128-aligned). Compute reads: 8 distinct b128 addrs/wave, 8-lane
// same-address broadcast -> conflict-free; 2 b128 per thread per h2 covers
// 4i x 4j x 2h = 32 (out,h) pairs. VALU: pk_add + pk_max + fdot2 = 3 insts
// per 4 pairs. 8 partials per output reduced via LDS (stride 17, 2-way free).
// LDS-issue/CU ~3.5K cyc, VALU ~3.1K cyc (was ~28K LDS in R7).
// ---------------------------------------------------------------------------
#define ST 36
__global__ __launch_bounds__(512) void kPair(
    const unsigned int* __restrict__ Ah, const unsigned int* __restrict__ Wh,
    const unsigned int* __restrict__ ubh, const float* __restrict__ W2,
    const float* __restrict__ b2, float* __restrict__ out) {
  __shared__ __align__(16) unsigned int sbuf[2 * 128 * ST];  // 36.9 KB
  __shared__ unsigned int w2h[128];
  unsigned int* aT = sbuf;             // [h2][i-row], half2 elements
  unsigned int* wT = sbuf + 128 * ST;  // [h2][j-row]

  const int b = blockIdx.z;
  const int i0 = blockIdx.y * 32;
  const int j0 = blockIdx.x * 32;
  const int t = threadIdx.x;  // 0..511

  // ---- stage: 32 rows x 128 h2 per array, ub folded into aT (f16 add) ----
  const int hh2 = t & 127;    // h2 (coalesced global reads)
  const int rg2 = t >> 7;     // 0..3 -> 8 rows each
  if (t < 128) {
    h2_t v; v.x = (_Float16)W2[2 * t]; v.y = (_Float16)W2[2 * t + 1];
    w2h[t] = h2u(v);
  }
  const h2_t ubv = uh2(ubh[b * 128 + hh2]);
  const unsigned int* Ap = Ah + (b * N + i0) * 128 + hh2;
  const unsigned int* Wp_ = Wh + (b * N + j0) * 128 + hh2;
#pragma unroll
  for (int g = 0; g < 2; ++g) {
    const int rb = rg2 * 8 + g * 4;
    // gather 4 rows into regs, write one b128 (fewer conflicted LDS writes)
    const h2_t x0 = uh2(Ap[(rb + 0) * 128]) + ubv;
    const h2_t x1 = uh2(Ap[(rb + 1) * 128]) + ubv;
    const h2_t x2 = uh2(Ap[(rb + 2) * 128]) + ubv;
    const h2_t x3 = uh2(Ap[(rb + 3) * 128]) + ubv;
    uint4 av; av.x = h2u(x0); av.y = h2u(x1); av.z = h2u(x2); av.w = h2u(x3);
    uint4 wv; wv.x = Wp_[(rb + 0) * 128]; wv.y = Wp_[(rb + 1) * 128];
    wv.z = Wp_[(rb + 2) * 128]; wv.w = Wp_[(rb + 3) * 128];
    *(uint4*)(aT + hh2 * ST + rb) = av;
    *(uint4*)(wT + hh2 * ST + rb) = wv;
  }
  __syncthreads();

  // ---- compute: wave = h-slice (hs uniform per wave) ----
  const int hs = t >> 6;        // 0..7
  const int pos = t & 63;
  const int qi = pos & 7;       // i-quad
  const int qj = pos >> 3;      // j-quad
  float acc[16];
#pragma unroll
  for (int k = 0; k < 16; ++k) acc[k] = 0.f;
  const unsigned int* ap = aT + 4 * qi;
  const unsigned int* wp = wT + 4 * qj;
  const h2_t hz = {(_Float16)0.f, (_Float16)0.f};
  const int h2a = hs * 16;
#pragma unroll 4
  for (int h2i = h2a; h2i < h2a + 16; ++h2i) {
    const uint4 a4 = *(const uint4*)(ap + h2i * ST);
    const uint4 w4 = *(const uint4*)(wp + h2i * ST);
    const h2_t w2v = uh2(w2h[h2i]);
    const h2_t aa0 = uh2(a4.x), aa1 = uh2(a4.y), aa2 = uh2(a4.z),
               aa3 = uh2(a4.w);
    const h2_t ww0 = uh2(w4.x), ww1 = uh2(w4.y), ww2 = uh2(w4.z),
               ww3 = uh2(w4.w);
#pragma unroll
    for (int si = 0; si < 4; ++si) {
      const h2_t av = (si == 0) ? aa0 : (si == 1) ? aa1 : (si == 2) ? aa2
                                                                    : aa3;
#pragma unroll
      for (int sj = 0; sj < 4; ++sj) {
        const h2_t wv = (sj == 0) ? ww0 : (sj == 1) ? ww1 : (sj == 2) ? ww2
                                                                      : ww3;
        h2_t s = av + wv;                        // v_pk_add_f16
        s = __builtin_elementwise_max(s, hz);    // v_pk_max_f16
        acc[si * 4 + sj] =
            __builtin_amdgcn_fdot2(s, w2v, acc[si * 4 + sj], false);
      }
    }
  }
  __syncthreads();

  // ---- reduce 8 h-slice partials per output via LDS (overlay on sbuf) ----
  float* part = (float*)sbuf;  // 512*17 = 8704 floats = 34.8 KB <= 36.9 KB
#pragma unroll
  for (int k = 0; k < 16; ++k) part[t * 17 + k] = acc[k];  // 2-way banks
  __syncthreads();

  const float bb = b2[0];
  const int oid = 2 * t;
  const int pos2 = oid >> 4;   // 0..63
  const int kk = oid & 15;     // even
  float s0 = 0.f, s1 = 0.f;
#pragma unroll
  for (int hsx = 0; hsx < 8; ++hsx) {
    const int base = (hsx * 64 + pos2) * 17;
    s0 += part[base + kk];
    s1 += part[base + kk + 1];
  }
  const int i = 4 * (pos2 & 7) + (kk >> 2);
  const int j = 4 * (pos2 >> 3) + (kk & 3);
  float2 o; o.x = s0 + bb; o.y = s1 + bb;
  *(float2*)(out + (b * N + i0 + i) * N + j0 + j) = o;
}

extern "C" void kernel_launch(void* const* d_in, const int* in_sizes, int n_in,
                              void* d_out, int out_size, void* d_ws, size_t ws_size,
                              hipStream_t stream) {
  const float* x  = (const float*)d_in[0];  // [B,N,F]
  const float* Wp = (const float*)d_in[1];  // [F,F]
  const float* W1 = (const float*)d_in[2];  // [3F,H]
  const float* b1 = (const float*)d_in[3];  // [H]
  const float* W2 = (const float*)d_in[4];  // [H,1]
  const float* b2 = (const float*)d_in[5];  // [1]
  float* out = (float*)d_out;               // [B,N,N,1]

  unsigned int* ws = (unsigned int*)d_ws;
  unsigned int* Ah  = ws;                    // B*N*128 half2 = 512 KB
  unsigned int* Wh  = Ah + B * N * 128;      // 512 KB
  unsigned int* ubh = Wh + B * N * 128;      // B*128 half2 = 2 KB
  // all of Ah/Wh/ubh written by kAW before kPair reads

  kAW<<<dim3(256), dim3(512), 0, stream>>>(x, Wp, W1, b1, ubh, Ah, Wh);
  kPair<<<dim3(N / 32, N / 32, B), dim3(512), 0, stream>>>(Ah, Wh, ubh, W2,
                                                           b2, out);
}